// Round 4
// baseline (183.665 us; speedup 1.0000x reference)
//
#include <hip/hip_runtime.h>

// Cholesky-from-partial-correlations.
//   out[b,i,j] = z_j * sqrt( prod_{k<j} (1 - z_k^2) )  for j < i;  1 on diag; 0 above.
// v4: grid-stride — 2048 blocks (8192 waves, full 32-wave/CU residency),
// each wave processes 16 rows: row = wv + t*8192. Since 8192 % 256 == 0, the
// matrix-row index i is LOOP-INVARIANT per wave: all masks, diagonal selects
// and scan bcast-skip branches hoist; only the batch advances (constant
// pointer strides). This amortizes the 32768 one-shot workgroup dispatches of
// v1 (~1 WG/cyc at the CP ≈ 13.6 us — same order as the whole kernel) and
// software-pipelines the row loads (prefetch t+1 while processing t).
// Refuted levers intentionally absent: NT stores (v2: +7 us HBM write drain —
// output must stay in L3), XCD swizzle + read clamp (v3: −5 us; input elements
// are each consumed exactly once, there is no cross-row reuse to localize).
// Wave prefix product via all-VALU DPP scan. Raw v_sqrt_f32 (err budget >> 1 ulp).

#define SIZE 256
#define BATCH 512
#define M (SIZE * (SIZE - 1) / 2)     // 32640
#define TOTAL (BATCH * M)             // 16711680
#define NWAVES 8192                   // resident waves (32/CU * 256 CU)
#define NBLOCKS (NWAVES / 4)          // 2048 blocks of 4 waves
#define NITER (BATCH * SIZE / NWAVES) // 16 rows per wave
#define STEP (32 * M)                 // input floats per iteration (32 batches)
#define DSTEP ((size_t)NWAVES * SIZE) // output floats per iteration

// 4-byte-aligned float4 — lets the backend emit an unaligned dwordx4
typedef float f4u __attribute__((ext_vector_type(4), aligned(4)));
// 16-byte-aligned float4 for the output stores
typedef float f4a __attribute__((ext_vector_type(4), aligned(16)));

// p *= dpp_shifted(p); invalid lanes contribute 1.0f (identity) via `old`
template <int CTRL, int ROW_MASK>
__device__ __forceinline__ float scan_mul(float p) {
    int sh = __builtin_amdgcn_update_dpp(
        __builtin_bit_cast(int, 1.0f),
        __builtin_bit_cast(int, p),
        CTRL, ROW_MASK, 0xF, false);
    return p * __builtin_bit_cast(float, sh);
}

// whole-wave shift right by 1; lane 0 gets 1.0f (exclusive-scan carry-in)
__device__ __forceinline__ float excl_shift_one(float p) {
    int r = __builtin_amdgcn_update_dpp(
        __builtin_bit_cast(int, 1.0f),
        __builtin_bit_cast(int, p),
        0x138 /* wave_shr:1 */, 0xF, 0xF, false);
    return __builtin_bit_cast(float, r);
}

__global__ __launch_bounds__(256, 4) void chol_from_z_kernel(
    const float* __restrict__ vec, float* __restrict__ out) {
    const int lane = threadIdx.x & 63;
    const int wib = __builtin_amdgcn_readfirstlane((int)threadIdx.x >> 6);
    const int wv = (int)blockIdx.x * 4 + wib;     // 0 .. NWAVES-1
    const int i = wv & 255;                       // matrix row — loop-invariant
    const int j0 = lane << 2;

    // loop-invariant per-lane masks (hoisted by construction)
    const bool m0 = (j0     < i), m1 = (j0 + 1 < i);
    const bool m2 = (j0 + 2 < i), m3 = (j0 + 3 < i);
    const bool d0 = (j0     == i), d1 = (j0 + 1 == i);
    const bool d2 = (j0 + 2 == i), d3 = (j0 + 3 == i);
    // only the globally-last row (b=511, i=255) lacks a full 1KiB window
    const bool last_wave = (wv == NWAVES - 1);

    const float* sp = vec + (wv >> 8) * M + ((i * (i - 1)) >> 1) + j0;
    float* dst = out + ((size_t)wv << 8) + j0;

    f4u cur = *(const f4u*)sp;                    // t=0 load: always in-bounds

#pragma unroll
    for (int t = 0; t < NITER; ++t) {
        // ---- prefetch row for t+1 (2 loads in flight per wave) ----
        f4u nxt = cur;
        if (t + 1 < NITER) {
            sp += STEP;
            if (!(last_wave && t + 1 == NITER - 1)) {   // scalar-uniform branch
                nxt = *(const f4u*)sp;
            } else {                                    // global tail: 255 valid elems
                nxt.x = sp[0]; nxt.y = sp[1]; nxt.z = sp[2];
                nxt.w = (j0 + 3 < 255) ? sp[3] : 0.f;   // lane 63 elem 3 is OOB
            }
        }

        // ---- process current row ----
        const float z0 = m0 ? cur.x : 0.f;
        const float z1 = m1 ? cur.y : 0.f;
        const float z2 = m2 ? cur.z : 0.f;
        const float z3 = m3 ? cur.w : 0.f;

        const float t0 = 1.f - z0 * z0;
        const float t1 = 1.f - z1 * z1;
        const float t2 = 1.f - z2 * z2;
        const float t3 = 1.f - z3 * z3;

        float p = (t0 * t1) * (t2 * t3);

        // wave64 inclusive prefix product — up to 6 VALU DPP steps;
        // bcast steps skipped for short rows (wave-uniform, loop-invariant)
        p = scan_mul<0x111, 0xF>(p);                  // row_shr:1
        p = scan_mul<0x112, 0xF>(p);                  // row_shr:2
        p = scan_mul<0x114, 0xF>(p);                  // row_shr:4
        p = scan_mul<0x118, 0xF>(p);                  // row_shr:8
        if (i >= 64)  p = scan_mul<0x142, 0xA>(p);    // row_bcast:15 -> rows 1,3
        if (i >= 128) p = scan_mul<0x143, 0xC>(p);    // row_bcast:31 -> rows 2,3

        float run = excl_shift_one(p);

        f4a o;
        o.x = d0 ? 1.f : z0 * __builtin_amdgcn_sqrtf(run); run *= t0;
        o.y = d1 ? 1.f : z1 * __builtin_amdgcn_sqrtf(run); run *= t1;
        o.z = d2 ? 1.f : z2 * __builtin_amdgcn_sqrtf(run); run *= t2;
        o.w = d3 ? 1.f : z3 * __builtin_amdgcn_sqrtf(run);

        *(f4a*)dst = o;            // dst 1 KiB-row-aligned; j0*4 is 16B multiple
        dst += DSTEP;
        cur = nxt;
    }
}

extern "C" void kernel_launch(void* const* d_in, const int* in_sizes, int n_in,
                              void* d_out, int out_size, void* d_ws, size_t ws_size,
                              hipStream_t stream) {
    const float* vec = (const float*)d_in[0];
    float* out = (float*)d_out;
    chol_from_z_kernel<<<NBLOCKS, 256, 0, stream>>>(vec, out);
}